// Round 8
// baseline (205.760 us; speedup 1.0000x reference)
//
#include <hip/hip_runtime.h>

#define NSYS 64
#define NAT  1000
#define NTOT (NSYS * NAT)          // 64000
#define MP   2200000               // MAX_PAIRS
#define CUT2 25.0f                 // cutoff^2
#define PADV 64000.0f              // padding_value = n
#define NBLK 250                   // 256-row blocks: 250 * 256 == 64000
#define CAP  104                   // per-row record capacity (max ~57 expected)
#define EB   512                   // eval blocks: 2 per CU, one round
#define LCN  1152                  // LDS atoms incl. overrun slack (j2 <= 1126)
#define NROWS 512                  // rows staged per emit block
#define POSB  4096                 // output positions per emit block

__device__ __forceinline__ float dist2f(float xi, float yi, float zi,
                                        float xj, float yj, float zj) {
    float dx = xi - xj, dy = yi - yj, dz = zi - zj;
    return fmaf(dz, dz, fmaf(dy, dy, dx * dx));
}

// popcount of mask over lanes strictly below me (2 VALU: v_mbcnt_lo/hi)
__device__ __forceinline__ int mbcnt(unsigned long long m) {
    unsigned lo = __builtin_amdgcn_mbcnt_lo((unsigned)m, 0u);
    return (int)__builtin_amdgcn_mbcnt_hi((unsigned)(m >> 32), lo);
}

// Persistent eval: block b = (system s = b>>3, stripe = b&7). Stage system
// coords once as float4 SoA in LDS; wave W = stripe*16+w handles rows
// r = (t odd ? 127-W : W) + 128t (alternating stripe balances load).
// Emits per-row records (j-r, d2bits) + per-row counts, and accumulates
// per-256-row block sums into bsum via device-scope atomics (order-free).
__global__ __launch_bounds__(1024) void k_eval(const float* __restrict__ coords,
                                               int* __restrict__ counts,
                                               int* __restrict__ bsum,
                                               uint2* __restrict__ qbuf) {
    __shared__ float4 lc[LCN];
    int s      = blockIdx.x >> 3;
    int stripe = blockIdx.x & 7;
    const float* cs = coords + s * (NAT * 3);
    for (int a = threadIdx.x; a < LCN; a += 1024)
        lc[a] = (a < NAT)
              ? make_float4(cs[3 * a], cs[3 * a + 1], cs[3 * a + 2], 0.0f)
              : make_float4(1.0e30f, 1.0e30f, 1.0e30f, 0.0f);
    __syncthreads();
    int w    = threadIdx.x >> 6;
    int lane = threadIdx.x & 63;
    int W    = stripe * 16 + w;
    for (int t = 0;; t++) {
        int r = ((t & 1) ? (127 - W) : W) + (t << 7);
        if (r >= NAT) { if (((t & 1) ? W : (127 - W)) + (t << 7) >= NAT) break; else continue; }
        float4 ci = lc[r];
        int grow = s * NAT + r;
        uint2* q = qbuf + (size_t)grow * CAP;
        int running = 0;
        int jb = r + 1;
        for (; jb + 127 < NAT; jb += 128) {          // full iters, no j checks
            int j  = jb + lane;
            float4 c0 = lc[j];
            float4 c1 = lc[j + 64];
            float d0 = dist2f(ci.x, ci.y, ci.z, c0.x, c0.y, c0.z);
            float d1 = dist2f(ci.x, ci.y, ci.z, c1.x, c1.y, c1.z);
            bool k0 = d0 < CUT2;
            bool k1 = d1 < CUT2;
            unsigned long long m0 = __ballot(k0);
            unsigned long long m1 = __ballot(k1);
            if (k0) {
                int rank = running + mbcnt(m0);
                if (rank < CAP)
                    q[rank] = make_uint2((unsigned)(j - r), __float_as_uint(d0));
            }
            int base1 = running + (int)__popcll(m0);
            if (k1) {
                int rank = base1 + mbcnt(m1);
                if (rank < CAP)
                    q[rank] = make_uint2((unsigned)(j + 64 - r), __float_as_uint(d1));
            }
            running = base1 + (int)__popcll(m1);
        }
        if (jb < NAT) {                              // single checked tail iter
            int j  = jb + lane;
            int j2 = j + 64;
            float4 c0 = lc[j];
            float4 c1 = lc[j2];
            float d0 = dist2f(ci.x, ci.y, ci.z, c0.x, c0.y, c0.z);
            float d1 = dist2f(ci.x, ci.y, ci.z, c1.x, c1.y, c1.z);
            bool k0 = (j  < NAT) && (d0 < CUT2);
            bool k1 = (j2 < NAT) && (d1 < CUT2);
            unsigned long long m0 = __ballot(k0);
            unsigned long long m1 = __ballot(k1);
            if (k0) {
                int rank = running + mbcnt(m0);
                if (rank < CAP)
                    q[rank] = make_uint2((unsigned)(j - r), __float_as_uint(d0));
            }
            int base1 = running + (int)__popcll(m0);
            if (k1) {
                int rank = base1 + mbcnt(m1);
                if (rank < CAP)
                    q[rank] = make_uint2((unsigned)(j2 - r), __float_as_uint(d1));
            }
            running = base1 + (int)__popcll(m1);
        }
        if (lane == 0) {
            counts[grow] = running;
            atomicAdd(&bsum[grow >> 8], running);
        }
    }
}

// Position-indexed emit + pad, fully coalesced, self-contained scan.
// Per block: scan bsum[250] in LDS -> bpre/total; locate covering 256-row
// block b0 for p0; stage+segment-scan 768 row counts; build lgoff[513];
// then thread covers 4 consecutive output slots, row via LDS search+walk,
// all 6 planes stored as float4. Pad slots share the same path.
// Out layout: [0)src [MP)dst [2MP)dst [3MP)src [4MP)d12 [5MP)d12 [6MP]npairs
__global__ __launch_bounds__(1024) void k_emit(const int* __restrict__ counts,
                                               const int* __restrict__ bsum,
                                               const uint2* __restrict__ qbuf,
                                               float* __restrict__ out) {
    __shared__ int bpre[256];
    __shared__ int scnt[768];
    __shared__ int lgoff[NROWS + 1];
    __shared__ int sh_b0, sh_r0, sh_tot;
    int t = threadIdx.x;

    // ---- scan bsum[250] -> exclusive bpre + total ----
    int v = 0;
    if (t < 256) {
        v = (t < NBLK) ? bsum[t] : 0;
        bpre[t] = v;
    }
    __syncthreads();
    for (int off = 1; off < 256; off <<= 1) {
        int u = 0;
        if (t < 256 && t >= off) u = bpre[t - off];
        __syncthreads();
        if (t < 256) bpre[t] += u;
        __syncthreads();
    }
    int incl = (t < 256) ? bpre[t] : 0;
    __syncthreads();
    if (t < 256) bpre[t] = incl - v;                 // exclusive; bpre[>=250]=total
    if (t == 255) sh_tot = incl;
    __syncthreads();
    int total = sh_tot;
    int p0 = blockIdx.x * POSB;

    // ---- find covering 256-row block b0 (largest with bpre <= p0) ----
    if (t == 0) sh_b0 = 0;
    __syncthreads();
    if (t < NBLK && bpre[t] <= p0) atomicMax(&sh_b0, t);
    __syncthreads();
    int b0 = sh_b0;

    // ---- stage + per-256-segment exclusive scan of 768 row counts ----
    int cv = 0;
    if (t < 768) {
        int g = b0 * 256 + t;
        cv = (g < NTOT) ? counts[g] : 0;
        scnt[t] = cv;
    }
    __syncthreads();
    for (int off = 1; off < 256; off <<= 1) {
        int u = 0;
        if (t < 768 && (t & 255) >= off) u = scnt[t - off];
        __syncthreads();
        if (t < 768) scnt[t] += u;
        __syncthreads();
    }
    int cincl = (t < 768) ? scnt[t] : 0;
    __syncthreads();
    if (t < 768) scnt[t] = cincl - cv;               // exclusive within segment
    __syncthreads();

    // ---- find start row r0 within block b0 ----
    if (t == 0) sh_r0 = (p0 < total) ? b0 * 256 : NTOT;
    __syncthreads();
    if (p0 < total && t < 256) {
        int g = b0 * 256 + t;
        if (g < NTOT && bpre[b0] + scnt[t] <= p0) atomicMax(&sh_r0, g);
    }
    __syncthreads();
    int r0 = sh_r0;

    // ---- build lgoff[0..512] ----
    if (t <= NROWS) {
        int r = r0 + t;
        int lg;
        if (r >= NTOT) lg = total;
        else {
            int blk = r >> 8;                        // b0..b0+2
            lg = bpre[blk] + scnt[(blk - b0) * 256 + (r & 255)];
        }
        lgoff[t] = lg;
    }
    __syncthreads();

    if (blockIdx.x == 0 && t == 0) out[6 * MP] = (float)total;  // npairs
    int valid = total < MP ? total : MP;

    int p4 = p0 + t * 4;
    if (p4 >= MP) return;
    int k = 0;
    for (int step = 256; step; step >>= 1) {
        int nk = k + step;
        if (nk <= NROWS - 1 && lgoff[nk] <= p4) k = nk;
    }
    float fs[4], fd[4], dd[4];
#pragma unroll
    for (int e = 0; e < 4; e++) {
        int p = p4 + e;
        if (p < valid) {
            while (k < NROWS - 1 && lgoff[k + 1] <= p) k++;
            int row = r0 + k;
            int local = p - lgoff[k];
            if (local > CAP - 1) local = CAP - 1;    // count>CAP guard (P~0)
            uint2 rec = qbuf[(size_t)row * CAP + local];
            fs[e] = (float)row;
            fd[e] = (float)(row + (int)rec.x);
            dd[e] = __uint_as_float(rec.y);
        } else {
            fs[e] = PADV; fd[e] = PADV; dd[e] = CUT2;
        }
    }
    if (p4 + 4 <= MP) {
        float4 vs = {fs[0], fs[1], fs[2], fs[3]};
        float4 vd = {fd[0], fd[1], fd[2], fd[3]};
        float4 vv = {dd[0], dd[1], dd[2], dd[3]};
        *(float4*)(out + p4)          = vs;
        *(float4*)(out + MP + p4)     = vd;
        *(float4*)(out + 2 * MP + p4) = vd;
        *(float4*)(out + 3 * MP + p4) = vs;
        *(float4*)(out + 4 * MP + p4) = vv;
        *(float4*)(out + 5 * MP + p4) = vv;
    } else {
#pragma unroll
        for (int e = 0; e < 4; e++) {
            int p = p4 + e;
            if (p < MP) {
                out[p]          = fs[e];
                out[MP + p]     = fd[e];
                out[2 * MP + p] = fd[e];
                out[3 * MP + p] = fs[e];
                out[4 * MP + p] = dd[e];
                out[5 * MP + p] = dd[e];
            }
        }
    }
}

extern "C" void kernel_launch(void* const* d_in, const int* in_sizes, int n_in,
                              void* d_out, int out_size, void* d_ws, size_t ws_size,
                              hipStream_t stream) {
    const float* coords = (const float*)d_in[0];
    float* out = (float*)d_out;

    // Workspace: counts[64000] | bsum[256] | qbuf (8B-aligned:
    // 64256 ints = 257024 B before it, divisible by 8)
    int*   counts = (int*)d_ws;
    int*   bsum   = counts + NTOT;
    uint2* qbuf   = (uint2*)(bsum + 256);

    hipMemsetAsync(bsum, 0, NBLK * sizeof(int), stream);   // capture-legal
    k_eval<<<EB, 1024, 0, stream>>>(coords, counts, bsum, qbuf);
    int emit_blocks = (MP + POSB - 1) / POSB;              // 538
    k_emit<<<emit_blocks, 1024, 0, stream>>>(counts, bsum, qbuf, out);
}

// Round 9
// 111.380 us; speedup vs baseline: 1.8474x; 1.8474x over previous
//
#include <hip/hip_runtime.h>

#define NSYS 64
#define NAT  1000
#define NTOT (NSYS * NAT)          // 64000
#define MP   2200000               // MAX_PAIRS
#define CUT2 25.0f                 // cutoff^2
#define PADV 64000.0f              // padding_value = n
#define SCAN_BLOCKS 250            // 250 * 256 == 64000 exactly
#define CAP  104                   // per-row record capacity (max ~57 expected)
#define EB   512                   // eval blocks: 2 per CU, one round
#define LCN  1152                  // LDS atoms incl. tail overrun (j <= 1062)
#define NROWS 512                  // rows staged per emit block
#define POSB  4096                 // output positions per emit block

__device__ __forceinline__ float dist2f(float xi, float yi, float zi,
                                        float xj, float yj, float zj) {
    float dx = xi - xj, dy = yi - yj, dz = zi - zj;
    return fmaf(dz, dz, fmaf(dy, dy, dx * dx));
}

// popcount of mask over lanes strictly below me (2 VALU: v_mbcnt_lo/hi)
__device__ __forceinline__ int mbcnt(unsigned long long m) {
    unsigned lo = __builtin_amdgcn_mbcnt_lo((unsigned)m, 0u);
    return (int)__builtin_amdgcn_mbcnt_hi((unsigned)(m >> 32), lo);
}

// Emit one ballot group's kept pair (ascending-j order preserved).
__device__ __forceinline__ int emit_group(uint2* __restrict__ q, int running,
                                          bool k, int j, int r, float d,
                                          unsigned long long m) {
    if (k) {
        int rank = running + mbcnt(m);
        if (rank < CAP)
            q[rank] = make_uint2((unsigned)(j - r), __float_as_uint(d));
    }
    return running + (int)__popcll(m);
}

// Persistent eval: block b = (system s = b>>3, stripe = b&7). Stage system
// coords once as float4 SoA in LDS; wave W = stripe*16+w handles rows
// r = (t odd ? 127-W : W) + 128t (alternating stripe balances load).
// Inner loop unrolled 4x (stride 256): 4 independent ds_read_b128 in flight.
// Tail: <=4 checked stride-64 iterations. Exact (s,i,j) rank via in-order
// ballots. Emits per-row records (j-r, d2bits) + true per-row counts.
__global__ __launch_bounds__(1024) void k_eval(const float* __restrict__ coords,
                                               int* __restrict__ counts,
                                               uint2* __restrict__ qbuf) {
    __shared__ float4 lc[LCN];
    int s      = blockIdx.x >> 3;
    int stripe = blockIdx.x & 7;
    const float* cs = coords + s * (NAT * 3);
    for (int a = threadIdx.x; a < LCN; a += 1024)
        lc[a] = (a < NAT)
              ? make_float4(cs[3 * a], cs[3 * a + 1], cs[3 * a + 2], 0.0f)
              : make_float4(1.0e30f, 1.0e30f, 1.0e30f, 0.0f);
    __syncthreads();
    int w    = threadIdx.x >> 6;
    int lane = threadIdx.x & 63;
    int W    = stripe * 16 + w;
    for (int t = 0;; t++) {
        int r = ((t & 1) ? (127 - W) : W) + (t << 7);
        if (r >= NAT) { if (((t & 1) ? W : (127 - W)) + (t << 7) >= NAT) break; else continue; }
        float4 ci = lc[r];
        int grow = s * NAT + r;
        uint2* q = qbuf + (size_t)grow * CAP;
        int running = 0;
        int jb = r + 1;
        // full 256-wide iterations: all four j-groups < NAT guaranteed
        for (; jb + 255 < NAT; jb += 256) {
            int j = jb + lane;
            float4 c0 = lc[j];
            float4 c1 = lc[j + 64];
            float4 c2 = lc[j + 128];
            float4 c3 = lc[j + 192];
            float d0 = dist2f(ci.x, ci.y, ci.z, c0.x, c0.y, c0.z);
            float d1 = dist2f(ci.x, ci.y, ci.z, c1.x, c1.y, c1.z);
            float d2 = dist2f(ci.x, ci.y, ci.z, c2.x, c2.y, c2.z);
            float d3 = dist2f(ci.x, ci.y, ci.z, c3.x, c3.y, c3.z);
            bool k0 = d0 < CUT2;
            bool k1 = d1 < CUT2;
            bool k2 = d2 < CUT2;
            bool k3 = d3 < CUT2;
            unsigned long long m0 = __ballot(k0);
            unsigned long long m1 = __ballot(k1);
            unsigned long long m2 = __ballot(k2);
            unsigned long long m3 = __ballot(k3);
            running = emit_group(q, running, k0, j,       r, d0, m0);
            running = emit_group(q, running, k1, j + 64,  r, d1, m1);
            running = emit_group(q, running, k2, j + 128, r, d2, m2);
            running = emit_group(q, running, k3, j + 192, r, d3, m3);
        }
        // tail: <=4 checked 64-wide iterations
        for (; jb < NAT; jb += 64) {
            int j = jb + lane;
            float4 c0 = lc[j];
            float d0 = dist2f(ci.x, ci.y, ci.z, c0.x, c0.y, c0.z);
            bool k0 = (j < NAT) && (d0 < CUT2);
            unsigned long long m0 = __ballot(k0);
            running = emit_group(q, running, k0, j, r, d0, m0);
        }
        if (lane == 0) counts[grow] = running;
    }
}

// Level-1 scan: 250 blocks x 256 rows -> block-exclusive offs[] + block sums.
__global__ void k_scan_a(const int* __restrict__ counts, int* __restrict__ offs,
                         int* __restrict__ bsum) {
    __shared__ int tmp[256];
    int t = threadIdx.x;
    int g = blockIdx.x * 256 + t;
    int v = counts[g];
    tmp[t] = v;
    __syncthreads();
    for (int off = 1; off < 256; off <<= 1) {
        int u = (t >= off) ? tmp[t - off] : 0;
        __syncthreads();
        tmp[t] += u;
        __syncthreads();
    }
    offs[g] = tmp[t] - v;
    if (t == 255) bsum[blockIdx.x] = tmp[255];
}

// Position-indexed emit + pad, fully coalesced (proven R7 structure).
// Out layout: [0)src [MP)dst [2MP)dst [3MP)src [4MP)d12 [5MP)d12 [6MP]npairs
__global__ __launch_bounds__(1024) void k_emit(const int* __restrict__ offs,
                                               const int* __restrict__ bsum,
                                               const uint2* __restrict__ qbuf,
                                               float* __restrict__ out) {
    __shared__ int bpre[256];
    __shared__ int lgoff[NROWS + 1];
    __shared__ int sh_r0, sh_tot;
    int t = threadIdx.x;
    int v = 0;
    if (t < 256) {
        v = (t < SCAN_BLOCKS) ? bsum[t] : 0;
        bpre[t] = v;
    }
    __syncthreads();
    for (int off = 1; off < 256; off <<= 1) {
        int u = 0;
        if (t < 256 && t >= off) u = bpre[t - off];
        __syncthreads();
        if (t < 256) bpre[t] += u;
        __syncthreads();
    }
    int incl = (t < 256) ? bpre[t] : 0;
    __syncthreads();
    if (t < 256) bpre[t] = incl - v;                 // exclusive prefix
    if (t == 255) sh_tot = incl;                     // grand total
    __syncthreads();
    int total = sh_tot;

    int p0 = blockIdx.x * POSB;
    if (t == 0) {
        int lo = 0, hi = NTOT;                       // largest r: goff(r) <= p0
        while (lo < hi) {
            int mid = (lo + hi + 1) >> 1;
            int g = (mid < NTOT) ? offs[mid] + bpre[mid >> 8] : total;
            if (g <= p0) lo = mid; else hi = mid - 1;
        }
        sh_r0 = lo;
    }
    __syncthreads();
    int r0 = sh_r0;
    if (t <= NROWS) {
        int r = r0 + t;
        lgoff[t] = (r < NTOT) ? offs[r] + bpre[r >> 8] : total;
    }
    __syncthreads();

    if (blockIdx.x == 0 && t == 0) out[6 * MP] = (float)total;  // npairs
    int valid = total < MP ? total : MP;

    int p4 = p0 + t * 4;
    if (p4 >= MP) return;
    int k = 0;
    for (int step = 256; step; step >>= 1) {
        int nk = k + step;
        if (nk <= NROWS - 1 && lgoff[nk] <= p4) k = nk;
    }
    float fs[4], fd[4], dd[4];
#pragma unroll
    for (int e = 0; e < 4; e++) {
        int p = p4 + e;
        if (p < valid) {
            while (k < NROWS - 1 && lgoff[k + 1] <= p) k++;
            int row = r0 + k;
            int local = p - lgoff[k];
            if (local > CAP - 1) local = CAP - 1;    // count>CAP guard (P~0)
            uint2 rec = qbuf[(size_t)row * CAP + local];
            fs[e] = (float)row;
            fd[e] = (float)(row + (int)rec.x);
            dd[e] = __uint_as_float(rec.y);
        } else {
            fs[e] = PADV; fd[e] = PADV; dd[e] = CUT2;
        }
    }
    if (p4 + 4 <= MP) {
        float4 vs = {fs[0], fs[1], fs[2], fs[3]};
        float4 vd = {fd[0], fd[1], fd[2], fd[3]};
        float4 vv = {dd[0], dd[1], dd[2], dd[3]};
        *(float4*)(out + p4)          = vs;
        *(float4*)(out + MP + p4)     = vd;
        *(float4*)(out + 2 * MP + p4) = vd;
        *(float4*)(out + 3 * MP + p4) = vs;
        *(float4*)(out + 4 * MP + p4) = vv;
        *(float4*)(out + 5 * MP + p4) = vv;
    } else {
#pragma unroll
        for (int e = 0; e < 4; e++) {
            int p = p4 + e;
            if (p < MP) {
                out[p]          = fs[e];
                out[MP + p]     = fd[e];
                out[2 * MP + p] = fd[e];
                out[3 * MP + p] = fs[e];
                out[4 * MP + p] = dd[e];
                out[5 * MP + p] = dd[e];
            }
        }
    }
}

extern "C" void kernel_launch(void* const* d_in, const int* in_sizes, int n_in,
                              void* d_out, int out_size, void* d_ws, size_t ws_size,
                              hipStream_t stream) {
    const float* coords = (const float*)d_in[0];
    float* out = (float*)d_out;

    // Workspace: counts[64000] | offs[64000] | bsum[256] | qbuf (8B-aligned)
    int*   counts = (int*)d_ws;
    int*   offs   = counts + NTOT;
    int*   bsum   = offs + NTOT;
    uint2* qbuf   = (uint2*)(bsum + 256);

    int emit_blocks = (MP + POSB - 1) / POSB;        // 538
    k_eval<<<EB, 1024, 0, stream>>>(coords, counts, qbuf);
    k_scan_a<<<SCAN_BLOCKS, 256, 0, stream>>>(counts, offs, bsum);
    k_emit<<<emit_blocks, 1024, 0, stream>>>(offs, bsum, qbuf, out);
}